// Round 4
// baseline (716.437 us; speedup 1.0000x reference)
//
#include <hip/hip_runtime.h>

#define THRESH 0.1f

typedef float    f4 __attribute__((ext_vector_type(4)));
typedef float    f2 __attribute__((ext_vector_type(2)));
typedef _Float16 h8 __attribute__((ext_vector_type(8)));
typedef _Float16 h4 __attribute__((ext_vector_type(4)));
typedef _Float16 h2 __attribute__((ext_vector_type(2)));

// ---------------------------------------------------------------------------
// Merged weight norm (per-row reduction math identical to all prior rounds).
// Linear rows are written PERMUTED to HWC fanin order: dst[pix*64+c]=src[c*16+pix]
// ---------------------------------------------------------------------------
__global__ void wnorm_all(const float* __restrict__ c0v, const float* __restrict__ c0g,
                          const float* __restrict__ c1v, const float* __restrict__ c1g,
                          const float* __restrict__ c2v, const float* __restrict__ c2g,
                          const float* __restrict__ c3v, const float* __restrict__ c3g,
                          const float* __restrict__ lv,  const float* __restrict__ lg,
                          float* __restrict__ w0, float* __restrict__ w1,
                          float* __restrict__ w2, float* __restrict__ w3,
                          float* __restrict__ wl) {
    int rb = blockIdx.x;
    const float *v, *g; float* w; int fanin, row;
    if (rb < 8)        { v = c0v; g = c0g; w = w0; fanin = 18;   row = rb; }
    else if (rb < 24)  { v = c1v; g = c1g; w = w1; fanin = 72;   row = rb - 8; }
    else if (rb < 56)  { v = c2v; g = c2g; w = w2; fanin = 144;  row = rb - 24; }
    else if (rb < 120) { v = c3v; g = c3g; w = w3; fanin = 288;  row = rb - 56; }
    else               { v = lv;  g = lg;  w = wl; fanin = 1024; row = rb - 120; }
    const bool perm = (rb >= 120);

    const float* vr = v + (size_t)row * fanin;
    float ss = 0.f;
    for (int i = threadIdx.x; i < fanin; i += 64) { float x = vr[i]; ss = fmaf(x, x, ss); }
    #pragma unroll
    for (int off = 32; off > 0; off >>= 1) ss += __shfl_down(ss, off);
    ss = __shfl(ss, 0);
    float scale = g[row] / sqrtf(ss);
    float* wr = w + (size_t)row * fanin;
    for (int i = threadIdx.x; i < fanin; i += 64) {
        int d = perm ? (((i & 15) << 6) | (i >> 4)) : i;
        wr[d] = vr[i] * scale;
    }
}

// ---------------------------------------------------------------------------
// Fused conv3x3(SAME) + IAF + 2x2 avgpool.  f16/HWC inter-layer tensors.
// R10: L2/L3 CG doubled (halved LDS read traffic).
// R11: TP=2 time-pairing for L2/L3 -- both are at 1 wave/SIMD (occupancy
// structurally capped), so they were latency-bound (VALUBusy 40%). conv(t)
// and conv(t+1) are independent; computing a pair with interleaved fma
// chains gives 2 dependency chains per SIMD (ILP substitutes for missing
// TLP), halves barriers, and shares weight scalar-loads. IAF recurrence
// stays strictly sequential (vmem A then B) and per-chain fma order
// (o,cid,k asc) is untouched -> bit-exact. 4 LDS slabs when TP=2.
// ---------------------------------------------------------------------------
template<int CIN, int H, int COUT, int CG, int WX, int SEGS, int BDIM, int PSB, int TP>
__launch_bounds__(BDIM)
__global__ void conv_iaf_pool(const void* __restrict__ in_, const float* __restrict__ w,
                              _Float16* __restrict__ out, int B, int T) {
    constexpr bool HIN  = (CIN % 8 == 0);     // f16 HWC input path
    constexpr int Hp    = H / 2;
    constexpr int PP    = Hp * Hp;
    constexpr int HH    = H * H;
    constexpr int WY    = 64 / WX;
    constexpr int NW    = BDIM / 64;
    constexpr int NWps  = NW / SEGS;
    constexpr int XW    = H / WX;             // waves across x (L0: 2, else 1)
    constexpr int YWV   = NWps / XW;
    constexpr int RPB   = YWV * WY;           // conv rows per block
    constexpr int STRIPS= H / RPB;
    constexpr int CGRP  = COUT / (CG * SEGS);
    constexpr int SR    = RPB + 2;
    constexpr int COLS  = H + 2;
    constexpr int SLABB = SR * COLS * PSB;    // slab bytes
    constexpr bool FULLY= (RPB == H);
    constexpr int R0    = FULLY ? 1 : 0;
    constexpr int NR    = FULLY ? H : SR;
    constexpr int UPC   = HIN ? (CIN / 8) : 1;    // staging units per position
    constexpr int NU    = NR * H * UPC;
    constexpr int ITERS = (NU + BDIM - 1) / BDIM;
    constexpr bool GUARD= !(FULLY && (NU % BDIM == 0));

    __shared__ alignas(16) char slab[2 * TP][SLABB];

    const int tid = threadIdx.x;
    const int G = gridDim.x, bx = blockIdx.x;
    const int pb = (bx & 7) * (G >> 3) + (bx >> 3);   // XCD clustering
    const int cgb   = pb % CGRP;
    const int strip = (pb / CGRP) % STRIPS;
    const int b     = pb / (CGRP * STRIPS);

    const int wid = tid >> 6, l = tid & 63;
    const int seg = wid / NWps;
    const int wlv = wid % NWps;
    const int xw = wlv % XW, yw = wlv / XW;
    const int xl = l % WX, ylw = l / WX;
    const int x  = xw * WX + xl;
    const int yy = yw * WY + ylw;
    const int y0 = strip * RPB;
    const int y  = y0 + yy;

    const int c0 = __builtin_amdgcn_readfirstlane((cgb * SEGS + seg) * CG);
    const float* __restrict__ wu = w + (size_t)c0 * (CIN * 9);

    // patch base byte offsets
    int addrB[9];
    #pragma unroll
    for (int dr = 0; dr < 3; ++dr)
        #pragma unroll
        for (int dc = 0; dc < 3; ++dc)
            addrB[dr * 3 + dc] = ((yy + dr) * COLS + (x + dc)) * PSB;

    // staging maps (lane-invariant over t)
    int goff[ITERS], loffB[ITERS];
    #pragma unroll
    for (int i = 0; i < ITERS; ++i) {
        const int idx = tid + i * BDIM;
        int j, gx, rr0;
        if constexpr (HIN) { j = idx % UPC; gx = (idx / UPC) % H; rr0 = idx / (UPC * H); }
        else               { j = 0;         gx = idx % H;         rr0 = (idx / H) % NR; }
        const int rr = R0 + rr0;
        const int gy = y0 - 1 + rr;
        const bool ok = (idx < NU) && ((unsigned)gy < (unsigned)H);
        if constexpr (HIN) goff[i] = ok ? ((gy * H + gx) * UPC + j) : -1;
        else               goff[i] = ok ? (gy * H + gx) : -1;
        loffB[i] = ok ? ((rr * COLS + (gx + 1)) * PSB + 16 * j) : -1;
    }

    constexpr bool WREG = !HIN && (CG * CIN * 9) <= 80;   // L0 only
    float wreg[WREG ? (CG * CIN * 9) : 1];
    if constexpr (WREG) {
        #pragma unroll
        for (int i = 0; i < CG * CIN * 9; ++i) wreg[i] = wu[i];
    }

    // zero all slabs (halo rows/cols persist as zeros)
    for (int i = tid; i < (2 * TP * SLABB) / 4; i += BDIM) ((int*)slab)[i] = 0;
    __syncthreads();

    float vmem[CG];
    #pragma unroll
    for (int c = 0; c < CG; ++c) vmem[c] = 0.f;

    f4 pf[TP][ITERS];
    #define GATHER(ph, t_)                                                        \
        if constexpr (HIN) {                                                      \
            const f4* inb = (const f4*)in_ + (size_t)(b * T + (t_)) * (HH * UPC); \
            _Pragma("unroll")                                                     \
            for (int i = 0; i < ITERS; ++i) {                                     \
                f4 r_ = {0.f, 0.f, 0.f, 0.f};                                     \
                if (!GUARD || goff[i] >= 0) r_ = inb[goff[i]];                    \
                pf[ph][i] = r_;                                                   \
            }                                                                     \
        } else {                                                                  \
            const float* inb = (const float*)in_ + (size_t)(b * T + (t_)) * (CIN * HH); \
            _Pragma("unroll")                                                     \
            for (int i = 0; i < ITERS; ++i) {                                     \
                f4 r_ = {0.f, 0.f, 0.f, 0.f};                                     \
                if (goff[i] >= 0) { r_.x = inb[goff[i]]; r_.y = inb[goff[i] + HH]; } \
                pf[ph][i] = r_;                                                   \
            }                                                                     \
        }
    #define STAGE(buf, ph)                                                        \
        _Pragma("unroll")                                                         \
        for (int i = 0; i < ITERS; ++i) {                                         \
            if (!GUARD || loffB[i] >= 0) {                                        \
                if constexpr (HIN) *(f4*)(&slab[buf][loffB[i]]) = pf[ph][i];      \
                else { f2 v2_; v2_.x = pf[ph][i].x; v2_.y = pf[ph][i].y;          \
                       *(f2*)(&slab[buf][loffB[i]]) = v2_; }                      \
            }                                                                     \
        }

    // single-frame conv (TP=1 path)
    auto conv1 = [&](const char* sb, float* acc) {
        #pragma unroll
        for (int c = 0; c < CG; ++c) acc[c] = 0.f;
        if constexpr (HIN) {
            #pragma unroll
            for (int o = 0; o < CIN / 8; ++o) {
                h8 P[9];
                #pragma unroll
                for (int k = 0; k < 9; ++k)
                    P[k] = *(const h8*)(sb + addrB[k] + 16 * o);
                #pragma unroll
                for (int cid = 0; cid < 8; ++cid) {
                    const int ci = 8 * o + cid;
                    #pragma unroll
                    for (int c = 0; c < CG; ++c)
                        #pragma unroll
                        for (int k = 0; k < 9; ++k)
                            acc[c] = fmaf((float)P[k][cid],
                                          wu[(size_t)(c * CIN + ci) * 9 + k], acc[c]);
                }
            }
        } else {
            f2 P[9];
            #pragma unroll
            for (int k = 0; k < 9; ++k)
                P[k] = *(const f2*)(sb + addrB[k]);
            #pragma unroll
            for (int cid = 0; cid < 2; ++cid)
                #pragma unroll
                for (int c = 0; c < CG; ++c)
                    #pragma unroll
                    for (int k = 0; k < 9; ++k)
                        acc[c] = fmaf(P[k][cid],
                                      WREG ? wreg[(c * CIN + cid) * 9 + k]
                                           : wu[(size_t)(c * CIN + cid) * 9 + k],
                                      acc[c]);
        }
    };

    // dual-frame conv (TP=2 path): two independent fma chains interleaved at
    // the innermost level; weight value shared. Per-chain order identical.
    auto conv2 = [&](const char* sbA, const char* sbB, float* accA, float* accB) {
        #pragma unroll
        for (int c = 0; c < CG; ++c) { accA[c] = 0.f; accB[c] = 0.f; }
        if constexpr (HIN) {
            #pragma unroll
            for (int o = 0; o < CIN / 8; ++o) {
                h8 PA[9], PB[9];
                #pragma unroll
                for (int k = 0; k < 9; ++k) {
                    PA[k] = *(const h8*)(sbA + addrB[k] + 16 * o);
                    PB[k] = *(const h8*)(sbB + addrB[k] + 16 * o);
                }
                #pragma unroll
                for (int cid = 0; cid < 8; ++cid) {
                    const int ci = 8 * o + cid;
                    #pragma unroll
                    for (int c = 0; c < CG; ++c)
                        #pragma unroll
                        for (int k = 0; k < 9; ++k) {
                            const float wv = wu[(size_t)(c * CIN + ci) * 9 + k];
                            accA[c] = fmaf((float)PA[k][cid], wv, accA[c]);
                            accB[c] = fmaf((float)PB[k][cid], wv, accB[c]);
                        }
                }
            }
        }
    };

    auto fire = [&](float* acc, int t_) {
        float sv[CG];
        #pragma unroll
        for (int c = 0; c < CG; ++c) {
            vmem[c] += acc[c];
            float s = (vmem[c] >= THRESH) ? 1.f : 0.f;
            vmem[c] -= THRESH * s;
            float sum = s;                         // exact 0/1 sums
            sum += __shfl_xor(sum, 1);
            sum += __shfl_xor(sum, WX);
            sv[c] = 0.25f * sum;                   // in {0,.25,.5,.75,1} -- exact f16
        }
        if (((xl | ylw) & 1) == 0) {
            const size_t ob = ((size_t)(b * T + t_) * PP + (y >> 1) * Hp + (x >> 1)) * COUT + c0;
            if constexpr (CG == 4) {
                h4 hv = {(_Float16)sv[0], (_Float16)sv[1], (_Float16)sv[2], (_Float16)sv[3]};
                *(h4*)(out + ob) = hv;
            } else if constexpr (CG == 2) {
                h2 hv = {(_Float16)sv[0], (_Float16)sv[1]};
                *(h2*)(out + ob) = hv;
            } else {
                out[ob] = (_Float16)sv[0];
            }
        }
    };

    if constexpr (TP == 1) {
        {   // prologue: stage frame 0, prefetch frame 1
            GATHER(0, 0)
            STAGE(0, 0)
            GATHER(0, 1)
        }
        __syncthreads();
        for (int t = 0; t < T; ++t) {
            if (t + 1 < T) { STAGE((t + 1) & 1, 0) }
            if (t + 2 < T) { GATHER(0, t + 2) }
            float acc[CG];
            conv1(slab[t & 1], acc);
            fire(acc, t);
            __syncthreads();                       // single barrier per timestep
        }
    } else {
        {   // prologue: stage frames 0,1 into slabs 0,1; prefetch frames 2,3
            GATHER(0, 0)
            GATHER(1, 1)
            STAGE(0, 0)
            STAGE(1, 1)
            GATHER(0, 2)
            GATHER(1, 3)
        }
        __syncthreads();
        for (int tt = 0; tt < T; tt += 2) {        // T even
            const int p = (tt >> 1) & 1;           // current pair slabs: 2p, 2p+1
            if (tt + 2 < T) { STAGE(2 * (p ^ 1), 0) STAGE(2 * (p ^ 1) + 1, 1) }
            if (tt + 4 < T) { GATHER(0, tt + 4) GATHER(1, tt + 5) }
            float accA[CG], accB[CG];
            conv2(&slab[2 * p][0], &slab[2 * p + 1][0], accA, accB);
            fire(accA, tt);
            fire(accB, tt + 1);
            __syncthreads();                       // single barrier per PAIR
        }
    }
    #undef GATHER
    #undef STAGE
}

// ---------------------------------------------------------------------------
// Linear: out (1600, 11) = h (1600, 1024 f16 HWC) @ wl_perm^T (11, 1024)
// ---------------------------------------------------------------------------
__global__ void linear_kernel(const _Float16* __restrict__ h, const float* __restrict__ w,
                              float* __restrict__ out) {
    __shared__ float hs[1024];
    __shared__ float part[16][17];
    const int n = blockIdx.x;
    for (int i = threadIdx.x; i < 1024; i += blockDim.x)
        hs[i] = (float)h[(size_t)n * 1024 + i];
    __syncthreads();
    const int j = threadIdx.x & 15, ch = threadIdx.x >> 4;
    float acc = 0.f;
    if (j < 11) {
        const float* wr = w + (size_t)j * 1024 + ch * 64;
        const float* hh = hs + ch * 64;
        #pragma unroll 8
        for (int k = 0; k < 64; ++k) acc = fmaf(hh[k], wr[k], acc);
    }
    part[j][ch] = acc;
    __syncthreads();
    if (threadIdx.x < 11) {
        float s = 0.f;
        #pragma unroll
        for (int cc = 0; cc < 16; ++cc) s += part[threadIdx.x][cc];
        out[(size_t)n * 11 + threadIdx.x] = s;
    }
}

// ---------------------------------------------------------------------------
extern "C" void kernel_launch(void* const* d_in, const int* in_sizes, int n_in,
                              void* d_out, int out_size, void* d_ws, size_t ws_size,
                              hipStream_t stream) {
    const int B = 32, T = 50;

    const float* x   = (const float*)d_in[0];
    const float* c0v = (const float*)d_in[1];
    const float* c0g = (const float*)d_in[2];
    const float* c1v = (const float*)d_in[3];
    const float* c1g = (const float*)d_in[4];
    const float* c2v = (const float*)d_in[5];
    const float* c2g = (const float*)d_in[6];
    const float* c3v = (const float*)d_in[7];
    const float* c3g = (const float*)d_in[8];
    const float* lv  = (const float*)d_in[9];
    const float* lg  = (const float*)d_in[10];
    float* out = (float*)d_out;

    // Workspace layout
    float* ws = (float*)d_ws;
    float* w0 = ws;                    // 8*2*9     = 144
    float* w1 = w0 + 144;              // 16*8*9    = 1152
    float* w2 = w1 + 1152;             // 32*16*9   = 4608
    float* w3 = w2 + 4608;             // 64*32*9   = 18432
    float* wl = w3 + 18432;            // 11*1024   = 11264 (HWC-permuted)
    _Float16* bufA16 = (_Float16*)(ws + 40960);            // L0 out f16 HWC
    _Float16* bufB16 = (_Float16*)(ws + 40960 + 13107200); // L1 out f16 HWC
    // L2 out reuses bufA16; L3 out reuses bufB16.

    wnorm_all<<<131, 64, 0, stream>>>(c0v, c0g, c1v, c1g, c2v, c2g, c3v, c3g,
                                      lv, lg, w0, w1, w2, w3, wl);

    // <CIN,H,COUT,CG,WX,SEGS,BDIM,PSB,TP>  grid = B * CGRP * STRIPS
    conv_iaf_pool<2,  64, 8,  4, 32, 1, 256, 8 , 1><<<1024, 256, 0, stream>>>(x,       w0, bufA16, B, T); // L0
    conv_iaf_pool<8,  32, 16, 4, 32, 1, 256, 16, 1><<<512,  256, 0, stream>>>(bufA16,  w1, bufB16, B, T); // L1
    conv_iaf_pool<16, 16, 32, 4, 16, 1, 256, 48, 2><<<256,  256, 0, stream>>>(bufB16,  w2, bufA16, B, T); // L2 TP=2
    conv_iaf_pool<32, 8,  64, 2, 8,  2, 128, 80, 2><<<512,  128, 0, stream>>>(bufA16,  w3, bufB16, B, T); // L3 TP=2

    linear_kernel<<<B * T, 256, 0, stream>>>(bufB16, wl, out);
}

// Round 5
// 529.858 us; speedup vs baseline: 1.3521x; 1.3521x over previous
//
#include <hip/hip_runtime.h>

#define THRESH 0.1f

typedef float    f4 __attribute__((ext_vector_type(4)));
typedef float    f2 __attribute__((ext_vector_type(2)));
typedef _Float16 h8 __attribute__((ext_vector_type(8)));
typedef _Float16 h4 __attribute__((ext_vector_type(4)));
typedef _Float16 h2 __attribute__((ext_vector_type(2)));

// ---------------------------------------------------------------------------
// Merged weight norm (per-row reduction math identical to all prior rounds).
// Linear rows are written PERMUTED to HWC fanin order: dst[pix*64+c]=src[c*16+pix]
// ---------------------------------------------------------------------------
__global__ void wnorm_all(const float* __restrict__ c0v, const float* __restrict__ c0g,
                          const float* __restrict__ c1v, const float* __restrict__ c1g,
                          const float* __restrict__ c2v, const float* __restrict__ c2g,
                          const float* __restrict__ c3v, const float* __restrict__ c3g,
                          const float* __restrict__ lv,  const float* __restrict__ lg,
                          float* __restrict__ w0, float* __restrict__ w1,
                          float* __restrict__ w2, float* __restrict__ w3,
                          float* __restrict__ wl) {
    int rb = blockIdx.x;
    const float *v, *g; float* w; int fanin, row;
    if (rb < 8)        { v = c0v; g = c0g; w = w0; fanin = 18;   row = rb; }
    else if (rb < 24)  { v = c1v; g = c1g; w = w1; fanin = 72;   row = rb - 8; }
    else if (rb < 56)  { v = c2v; g = c2g; w = w2; fanin = 144;  row = rb - 24; }
    else if (rb < 120) { v = c3v; g = c3g; w = w3; fanin = 288;  row = rb - 56; }
    else               { v = lv;  g = lg;  w = wl; fanin = 1024; row = rb - 120; }
    const bool perm = (rb >= 120);

    const float* vr = v + (size_t)row * fanin;
    float ss = 0.f;
    for (int i = threadIdx.x; i < fanin; i += 64) { float x = vr[i]; ss = fmaf(x, x, ss); }
    #pragma unroll
    for (int off = 32; off > 0; off >>= 1) ss += __shfl_down(ss, off);
    ss = __shfl(ss, 0);
    float scale = g[row] / sqrtf(ss);
    float* wr = w + (size_t)row * fanin;
    for (int i = threadIdx.x; i < fanin; i += 64) {
        int d = perm ? (((i & 15) << 6) | (i >> 4)) : i;
        wr[d] = vr[i] * scale;
    }
}

// ---------------------------------------------------------------------------
// Fused conv3x3(SAME) + IAF + 2x2 avgpool.  f16/HWC inter-layer tensors.
// R10: L2/L3 CG doubled (halved LDS read traffic).
// R11 (failed): TP=2 with fully-unrolled o loop -> scheduler hoisted all 72
//   ds_read_b128, VGPR hit the 256 cap, spilled to scratch (FETCH +300KB),
//   L3 2.3x slower.
// R12: TP=2 with ROLLED o loop (#pragma unroll 1). Live patch set bounded at
//   18 h8 = 72 VGPR per iteration; 4 independent fma chains per iteration
//   (2 frames x CG) supply the ILP that 1-wave/SIMD occupancy cannot. IAF
//   recurrence stays strictly sequential and per-chain fma order (o,cid,k
//   asc) is untouched -> bit-exact (R11 already verified TP=2 numerics).
// ---------------------------------------------------------------------------
template<int CIN, int H, int COUT, int CG, int WX, int SEGS, int BDIM, int PSB, int TP>
__launch_bounds__(BDIM)
__global__ void conv_iaf_pool(const void* __restrict__ in_, const float* __restrict__ w,
                              _Float16* __restrict__ out, int B, int T) {
    constexpr bool HIN  = (CIN % 8 == 0);     // f16 HWC input path
    constexpr int Hp    = H / 2;
    constexpr int PP    = Hp * Hp;
    constexpr int HH    = H * H;
    constexpr int WY    = 64 / WX;
    constexpr int NW    = BDIM / 64;
    constexpr int NWps  = NW / SEGS;
    constexpr int XW    = H / WX;             // waves across x (L0: 2, else 1)
    constexpr int YWV   = NWps / XW;
    constexpr int RPB   = YWV * WY;           // conv rows per block
    constexpr int STRIPS= H / RPB;
    constexpr int CGRP  = COUT / (CG * SEGS);
    constexpr int SR    = RPB + 2;
    constexpr int COLS  = H + 2;
    constexpr int SLABB = SR * COLS * PSB;    // slab bytes
    constexpr bool FULLY= (RPB == H);
    constexpr int R0    = FULLY ? 1 : 0;
    constexpr int NR    = FULLY ? H : SR;
    constexpr int UPC   = HIN ? (CIN / 8) : 1;    // staging units per position
    constexpr int NU    = NR * H * UPC;
    constexpr int ITERS = (NU + BDIM - 1) / BDIM;
    constexpr bool GUARD= !(FULLY && (NU % BDIM == 0));

    __shared__ alignas(16) char slab[2 * TP][SLABB];

    const int tid = threadIdx.x;
    const int G = gridDim.x, bx = blockIdx.x;
    const int pb = (bx & 7) * (G >> 3) + (bx >> 3);   // XCD clustering
    const int cgb   = pb % CGRP;
    const int strip = (pb / CGRP) % STRIPS;
    const int b     = pb / (CGRP * STRIPS);

    const int wid = tid >> 6, l = tid & 63;
    const int seg = wid / NWps;
    const int wlv = wid % NWps;
    const int xw = wlv % XW, yw = wlv / XW;
    const int xl = l % WX, ylw = l / WX;
    const int x  = xw * WX + xl;
    const int yy = yw * WY + ylw;
    const int y0 = strip * RPB;
    const int y  = y0 + yy;

    const int c0 = __builtin_amdgcn_readfirstlane((cgb * SEGS + seg) * CG);
    const float* __restrict__ wu = w + (size_t)c0 * (CIN * 9);

    // patch base byte offsets
    int addrB[9];
    #pragma unroll
    for (int dr = 0; dr < 3; ++dr)
        #pragma unroll
        for (int dc = 0; dc < 3; ++dc)
            addrB[dr * 3 + dc] = ((yy + dr) * COLS + (x + dc)) * PSB;

    // staging maps (lane-invariant over t)
    int goff[ITERS], loffB[ITERS];
    #pragma unroll
    for (int i = 0; i < ITERS; ++i) {
        const int idx = tid + i * BDIM;
        int j, gx, rr0;
        if constexpr (HIN) { j = idx % UPC; gx = (idx / UPC) % H; rr0 = idx / (UPC * H); }
        else               { j = 0;         gx = idx % H;         rr0 = (idx / H) % NR; }
        const int rr = R0 + rr0;
        const int gy = y0 - 1 + rr;
        const bool ok = (idx < NU) && ((unsigned)gy < (unsigned)H);
        if constexpr (HIN) goff[i] = ok ? ((gy * H + gx) * UPC + j) : -1;
        else               goff[i] = ok ? (gy * H + gx) : -1;
        loffB[i] = ok ? ((rr * COLS + (gx + 1)) * PSB + 16 * j) : -1;
    }

    constexpr bool WREG = !HIN && (CG * CIN * 9) <= 80;   // L0 only
    float wreg[WREG ? (CG * CIN * 9) : 1];
    if constexpr (WREG) {
        #pragma unroll
        for (int i = 0; i < CG * CIN * 9; ++i) wreg[i] = wu[i];
    }

    // zero all slabs (halo rows/cols persist as zeros)
    for (int i = tid; i < (2 * TP * SLABB) / 4; i += BDIM) ((int*)slab)[i] = 0;
    __syncthreads();

    float vmem[CG];
    #pragma unroll
    for (int c = 0; c < CG; ++c) vmem[c] = 0.f;

    f4 pf[TP][ITERS];
    #define GATHER(ph, t_)                                                        \
        if constexpr (HIN) {                                                      \
            const f4* inb = (const f4*)in_ + (size_t)(b * T + (t_)) * (HH * UPC); \
            _Pragma("unroll")                                                     \
            for (int i = 0; i < ITERS; ++i) {                                     \
                f4 r_ = {0.f, 0.f, 0.f, 0.f};                                     \
                if (!GUARD || goff[i] >= 0) r_ = inb[goff[i]];                    \
                pf[ph][i] = r_;                                                   \
            }                                                                     \
        } else {                                                                  \
            const float* inb = (const float*)in_ + (size_t)(b * T + (t_)) * (CIN * HH); \
            _Pragma("unroll")                                                     \
            for (int i = 0; i < ITERS; ++i) {                                     \
                f4 r_ = {0.f, 0.f, 0.f, 0.f};                                     \
                if (goff[i] >= 0) { r_.x = inb[goff[i]]; r_.y = inb[goff[i] + HH]; } \
                pf[ph][i] = r_;                                                   \
            }                                                                     \
        }
    #define STAGE(buf, ph)                                                        \
        _Pragma("unroll")                                                         \
        for (int i = 0; i < ITERS; ++i) {                                         \
            if (!GUARD || loffB[i] >= 0) {                                        \
                if constexpr (HIN) *(f4*)(&slab[buf][loffB[i]]) = pf[ph][i];      \
                else { f2 v2_; v2_.x = pf[ph][i].x; v2_.y = pf[ph][i].y;          \
                       *(f2*)(&slab[buf][loffB[i]]) = v2_; }                      \
            }                                                                     \
        }

    // single-frame conv (TP=1 path)
    auto conv1 = [&](const char* sb, float* acc) {
        #pragma unroll
        for (int c = 0; c < CG; ++c) acc[c] = 0.f;
        if constexpr (HIN) {
            #pragma unroll
            for (int o = 0; o < CIN / 8; ++o) {
                h8 P[9];
                #pragma unroll
                for (int k = 0; k < 9; ++k)
                    P[k] = *(const h8*)(sb + addrB[k] + 16 * o);
                #pragma unroll
                for (int cid = 0; cid < 8; ++cid) {
                    const int ci = 8 * o + cid;
                    #pragma unroll
                    for (int c = 0; c < CG; ++c)
                        #pragma unroll
                        for (int k = 0; k < 9; ++k)
                            acc[c] = fmaf((float)P[k][cid],
                                          wu[(size_t)(c * CIN + ci) * 9 + k], acc[c]);
                }
            }
        } else {
            f2 P[9];
            #pragma unroll
            for (int k = 0; k < 9; ++k)
                P[k] = *(const f2*)(sb + addrB[k]);
            #pragma unroll
            for (int cid = 0; cid < 2; ++cid)
                #pragma unroll
                for (int c = 0; c < CG; ++c)
                    #pragma unroll
                    for (int k = 0; k < 9; ++k)
                        acc[c] = fmaf(P[k][cid],
                                      WREG ? wreg[(c * CIN + cid) * 9 + k]
                                           : wu[(size_t)(c * CIN + cid) * 9 + k],
                                      acc[c]);
        }
    };

    // dual-frame conv (TP=2 path): ROLLED o loop (unroll 1) bounds the live
    // patch set to 18 h8 = 72 VGPR -- R11's full unroll hoisted all 72
    // ds_reads, hit the 256-VGPR cap and spilled. 4 independent fma chains
    // per iteration (2 frames x CG). Per-chain fma order identical.
    auto conv2 = [&](const char* sbA, const char* sbB, float* accA, float* accB) {
        #pragma unroll
        for (int c = 0; c < CG; ++c) { accA[c] = 0.f; accB[c] = 0.f; }
        if constexpr (HIN) {
            #pragma unroll 1
            for (int o = 0; o < CIN / 8; ++o) {
                h8 PA[9], PB[9];
                #pragma unroll
                for (int k = 0; k < 9; ++k) {
                    PA[k] = *(const h8*)(sbA + addrB[k] + 16 * o);
                    PB[k] = *(const h8*)(sbB + addrB[k] + 16 * o);
                }
                #pragma unroll
                for (int cid = 0; cid < 8; ++cid) {
                    const int ci = 8 * o + cid;
                    #pragma unroll
                    for (int c = 0; c < CG; ++c)
                        #pragma unroll
                        for (int k = 0; k < 9; ++k) {
                            const float wv = wu[(size_t)(c * CIN + ci) * 9 + k];
                            accA[c] = fmaf((float)PA[k][cid], wv, accA[c]);
                            accB[c] = fmaf((float)PB[k][cid], wv, accB[c]);
                        }
                }
            }
        }
    };

    auto fire = [&](float* acc, int t_) {
        float sv[CG];
        #pragma unroll
        for (int c = 0; c < CG; ++c) {
            vmem[c] += acc[c];
            float s = (vmem[c] >= THRESH) ? 1.f : 0.f;
            vmem[c] -= THRESH * s;
            float sum = s;                         // exact 0/1 sums
            sum += __shfl_xor(sum, 1);
            sum += __shfl_xor(sum, WX);
            sv[c] = 0.25f * sum;                   // in {0,.25,.5,.75,1} -- exact f16
        }
        if (((xl | ylw) & 1) == 0) {
            const size_t ob = ((size_t)(b * T + t_) * PP + (y >> 1) * Hp + (x >> 1)) * COUT + c0;
            if constexpr (CG == 4) {
                h4 hv = {(_Float16)sv[0], (_Float16)sv[1], (_Float16)sv[2], (_Float16)sv[3]};
                *(h4*)(out + ob) = hv;
            } else if constexpr (CG == 2) {
                h2 hv = {(_Float16)sv[0], (_Float16)sv[1]};
                *(h2*)(out + ob) = hv;
            } else {
                out[ob] = (_Float16)sv[0];
            }
        }
    };

    if constexpr (TP == 1) {
        {   // prologue: stage frame 0, prefetch frame 1
            GATHER(0, 0)
            STAGE(0, 0)
            GATHER(0, 1)
        }
        __syncthreads();
        for (int t = 0; t < T; ++t) {
            if (t + 1 < T) { STAGE((t + 1) & 1, 0) }
            if (t + 2 < T) { GATHER(0, t + 2) }
            float acc[CG];
            conv1(slab[t & 1], acc);
            fire(acc, t);
            __syncthreads();                       // single barrier per timestep
        }
    } else {
        {   // prologue: stage frames 0,1 into slabs 0,1; prefetch frames 2,3
            GATHER(0, 0)
            GATHER(1, 1)
            STAGE(0, 0)
            STAGE(1, 1)
            GATHER(0, 2)
            GATHER(1, 3)
        }
        __syncthreads();
        for (int tt = 0; tt < T; tt += 2) {        // T even
            const int p = (tt >> 1) & 1;           // current pair slabs: 2p, 2p+1
            if (tt + 2 < T) { STAGE(2 * (p ^ 1), 0) STAGE(2 * (p ^ 1) + 1, 1) }
            if (tt + 4 < T) { GATHER(0, tt + 4) GATHER(1, tt + 5) }
            float accA[CG], accB[CG];
            conv2(&slab[2 * p][0], &slab[2 * p + 1][0], accA, accB);
            fire(accA, tt);
            fire(accB, tt + 1);
            __syncthreads();                       // single barrier per PAIR
        }
    }
    #undef GATHER
    #undef STAGE
}

// ---------------------------------------------------------------------------
// Linear: out (1600, 11) = h (1600, 1024 f16 HWC) @ wl_perm^T (11, 1024)
// ---------------------------------------------------------------------------
__global__ void linear_kernel(const _Float16* __restrict__ h, const float* __restrict__ w,
                              float* __restrict__ out) {
    __shared__ float hs[1024];
    __shared__ float part[16][17];
    const int n = blockIdx.x;
    for (int i = threadIdx.x; i < 1024; i += blockDim.x)
        hs[i] = (float)h[(size_t)n * 1024 + i];
    __syncthreads();
    const int j = threadIdx.x & 15, ch = threadIdx.x >> 4;
    float acc = 0.f;
    if (j < 11) {
        const float* wr = w + (size_t)j * 1024 + ch * 64;
        const float* hh = hs + ch * 64;
        #pragma unroll 8
        for (int k = 0; k < 64; ++k) acc = fmaf(hh[k], wr[k], acc);
    }
    part[j][ch] = acc;
    __syncthreads();
    if (threadIdx.x < 11) {
        float s = 0.f;
        #pragma unroll
        for (int cc = 0; cc < 16; ++cc) s += part[threadIdx.x][cc];
        out[(size_t)n * 11 + threadIdx.x] = s;
    }
}

// ---------------------------------------------------------------------------
extern "C" void kernel_launch(void* const* d_in, const int* in_sizes, int n_in,
                              void* d_out, int out_size, void* d_ws, size_t ws_size,
                              hipStream_t stream) {
    const int B = 32, T = 50;

    const float* x   = (const float*)d_in[0];
    const float* c0v = (const float*)d_in[1];
    const float* c0g = (const float*)d_in[2];
    const float* c1v = (const float*)d_in[3];
    const float* c1g = (const float*)d_in[4];
    const float* c2v = (const float*)d_in[5];
    const float* c2g = (const float*)d_in[6];
    const float* c3v = (const float*)d_in[7];
    const float* c3g = (const float*)d_in[8];
    const float* lv  = (const float*)d_in[9];
    const float* lg  = (const float*)d_in[10];
    float* out = (float*)d_out;

    // Workspace layout
    float* ws = (float*)d_ws;
    float* w0 = ws;                    // 8*2*9     = 144
    float* w1 = w0 + 144;              // 16*8*9    = 1152
    float* w2 = w1 + 1152;             // 32*16*9   = 4608
    float* w3 = w2 + 4608;             // 64*32*9   = 18432
    float* wl = w3 + 18432;            // 11*1024   = 11264 (HWC-permuted)
    _Float16* bufA16 = (_Float16*)(ws + 40960);            // L0 out f16 HWC
    _Float16* bufB16 = (_Float16*)(ws + 40960 + 13107200); // L1 out f16 HWC
    // L2 out reuses bufA16; L3 out reuses bufB16.

    wnorm_all<<<131, 64, 0, stream>>>(c0v, c0g, c1v, c1g, c2v, c2g, c3v, c3g,
                                      lv, lg, w0, w1, w2, w3, wl);

    // <CIN,H,COUT,CG,WX,SEGS,BDIM,PSB,TP>  grid = B * CGRP * STRIPS
    conv_iaf_pool<2,  64, 8,  4, 32, 1, 256, 8 , 1><<<1024, 256, 0, stream>>>(x,       w0, bufA16, B, T); // L0
    conv_iaf_pool<8,  32, 16, 4, 32, 1, 256, 16, 1><<<512,  256, 0, stream>>>(bufA16,  w1, bufB16, B, T); // L1
    conv_iaf_pool<16, 16, 32, 4, 16, 1, 256, 48, 2><<<256,  256, 0, stream>>>(bufB16,  w2, bufA16, B, T); // L2 TP=2 rolled
    conv_iaf_pool<32, 8,  64, 2, 8,  2, 128, 80, 2><<<512,  128, 0, stream>>>(bufA16,  w3, bufB16, B, T); // L3 TP=2 rolled

    linear_kernel<<<B * T, 256, 0, stream>>>(bufB16, wl, out);
}